// Round 2
// baseline (549.412 us; speedup 1.0000x reference)
//
#include <hip/hip_runtime.h>

typedef unsigned short u16;
typedef __attribute__((ext_vector_type(8))) short short8;
typedef __attribute__((ext_vector_type(4))) float floatx4;

#define NB 64
#define HH 56
#define WW_ 56
#define CC 128
#define NHEADS 4
#define WS2 49
#define PAD 4      // P_T = P_L = 4
#define HID 512

__device__ __forceinline__ float bf2f(u16 u){ return __uint_as_float(((unsigned)u)<<16); }
__device__ __forceinline__ u16 f2bf(float f){
  unsigned u = __float_as_uint(f);
  return (u16)((u + 0x7FFFu + ((u>>16)&1u)) >> 16);
}
// pack two f32 -> one u32 of 2 bf16 (lo = a, hi = b)
__device__ __forceinline__ unsigned pk2(float a, float b){
  return ((unsigned)f2bf(b) << 16) | (unsigned)f2bf(a);
}
// tanh-approx GELU in sigmoid form: x * sigmoid(1.5957691*x*(1+0.044715*x^2))
__device__ __forceinline__ float gelu_f(float x){
  float u2 = x*(1.5957691216f + 0.0713548162f*x*x);
  return x / (1.f + __expf(-u2));
}
// element-wise fragment load (LDS); compiler merges to widest aligned DS op
__device__ __forceinline__ short8 ld_frag(const u16* p){
  short8 v;
  #pragma unroll
  for (int e = 0; e < 8; e++) v[e] = (short)p[e];
  return v;
}
// vector fragment load (global, provably 16B-aligned)
__device__ __forceinline__ short8 ld_frag_g(const u16* p){
  return *(const short8*)p;
}

// ---------------------------------------------------------------------------
// prep: fc1_w (C,HID) f32 -> bf16 [HID][C];  fc2_w (HID,C) f32 -> bf16 [C][HID]
//       spatial_w [h][i][j] f32 -> bf16 [h][i(64)][j(stride 68)], zero-padded
// ---------------------------------------------------------------------------
__global__ __launch_bounds__(256) void prep_k(
    const float* __restrict__ fc1_w, const float* __restrict__ fc2_w,
    const float* __restrict__ sw,
    u16* __restrict__ fc1_wT, u16* __restrict__ fc2_wT, u16* __restrict__ swT)
{
  int tid = blockIdx.x*256 + threadIdx.x;
  int nth = gridDim.x * 256;
  for (int idx = tid; idx < HID*CC; idx += nth) {
    int n = idx >> 7, k = idx & 127;
    fc1_wT[idx] = f2bf(fc1_w[k*HID + n]);
  }
  for (int idx = tid; idx < CC*HID; idx += nth) {
    int c = idx >> 9, h = idx & 511;
    fc2_wT[idx] = f2bf(fc2_w[h*CC + c]);
  }
  for (int idx = tid; idx < NHEADS*64*68; idx += nth) {
    int hd = idx / (64*68); int rem = idx - hd*64*68;
    int i = rem / 68, j = rem - i*68;
    swT[idx] = (i < WS2 && j < WS2) ? f2bf(sw[(hd*WS2 + i)*WS2 + j]) : (u16)0;
  }
}

// ---------------------------------------------------------------------------
// winmix: fused LN1 + shifted-window token mix (MFMA) + residual -> x2 (f32)
// (proven version, unchanged from the 506 us baseline)
// ---------------------------------------------------------------------------
__global__ __launch_bounds__(256, 2) void winmix_k(
    const float* __restrict__ x, const float* __restrict__ g1, const float* __restrict__ b1,
    const u16* __restrict__ swT, const float* __restrict__ sb,
    float* __restrict__ x2)
{
  __shared__ u16 wl[NHEADS*64*68];   // 34816 B, bf16 W [hd][i][j] stride 68
  __shared__ u16 xnt[CC*66];         // 16896 B, bf16 LN-out [c][j] stride 66
  __shared__ float sbl[NHEADS*WS2];  // 784 B
  int tid = threadIdx.x;
  int wvid = tid >> 6, lane = tid & 63;
  int ln = lane & 15, qd = lane >> 4;
  int b = blockIdx.x / 81; int wi = blockIdx.x - b*81;
  int wh = wi / 9, wwn = wi - wh*9;

  { // stage spatial weights: 4*64*68 u16 = 4352 uint2, 17 per thread
    const uint2* ws = (const uint2*)swT;
    uint2* wd = (uint2*)wl;
    #pragma unroll
    for (int r = 0; r < 17; r++) wd[tid + r*256] = ws[tid + r*256];
    if (tid < NHEADS*WS2) sbl[tid] = sb[tid];
  }

  // LN per window position (transposed write); jj>=49 writes zeros (K pad)
  float gl0 = g1[lane], gl1 = g1[lane+64];
  float bl0 = b1[lane], bl1 = b1[lane+64];
  for (int jj = wvid; jj < 64; jj += 4) {
    u16 o0 = 0, o1 = 0;
    if (jj < WS2) {
      int jr = jj / 7, jc = jj - jr*7;
      int pr = wh*7 + jr - PAD, pc = wwn*7 + jc - PAD;
      bool valid = (pr>=0) & (pr<HH) & (pc>=0) & (pc<WW_);
      float v0 = 0.f, v1 = 0.f;
      const float* px = x + ((size_t)((b*HH + pr)*WW_ + pc))*CC;
      if (valid) { v0 = px[lane]; v1 = px[lane+64]; }
      float s = v0 + v1, ss = v0*v0 + v1*v1;
      #pragma unroll
      for (int o = 32; o > 0; o >>= 1) { s += __shfl_xor(s, o); ss += __shfl_xor(ss, o); }
      float mu = s * (1.f/128.f);
      float var = ss * (1.f/128.f) - mu*mu;
      float rs = rsqrtf(var + 1e-5f);
      if (valid) {
        o0 = f2bf((v0 - mu)*rs*gl0 + bl0);
        o1 = f2bf((v1 - mu)*rs*gl1 + bl1);
      }
    }
    xnt[lane*66 + jj]      = o0;
    xnt[(lane+64)*66 + jj] = o1;
  }
  __syncthreads();

  // MFMA token mix: wave = head
  int hd = wvid;
  const u16* wbase = wl + hd*64*68;
  short8 af[4][2];
  #pragma unroll
  for (int mt = 0; mt < 4; mt++)
    #pragma unroll
    for (int ks = 0; ks < 2; ks++)
      af[mt][ks] = ld_frag(&wbase[(mt*16 + ln)*68 + ks*32 + qd*8]);
  short8 bf_[2][2];
  #pragma unroll
  for (int nt = 0; nt < 2; nt++)
    #pragma unroll
    for (int ks = 0; ks < 2; ks++)
      bf_[nt][ks] = ld_frag(&xnt[(hd*32 + nt*16 + ln)*66 + ks*32 + qd*8]);
  floatx4 acc[4][2];
  #pragma unroll
  for (int mt = 0; mt < 4; mt++)
    #pragma unroll
    for (int nt = 0; nt < 2; nt++)
      acc[mt][nt] = (floatx4){0.f,0.f,0.f,0.f};
  #pragma unroll
  for (int ks = 0; ks < 2; ks++)
    #pragma unroll
    for (int mt = 0; mt < 4; mt++)
      #pragma unroll
      for (int nt = 0; nt < 2; nt++)
        acc[mt][nt] = __builtin_amdgcn_mfma_f32_16x16x32_bf16(af[mt][ks], bf_[nt][ks], acc[mt][nt], 0, 0, 0);

  // epilogue: residual add + spatial bias + write (skip pad/cropped)
  #pragma unroll
  for (int mt = 0; mt < 4; mt++) {
    #pragma unroll
    for (int r = 0; r < 4; r++) {
      int i = mt*16 + qd*4 + r;
      if (i < WS2) {
        int ir = i / 7, ic = i - ir*7;
        int orow = wh*7 + ir - PAD, ocol = wwn*7 + ic - PAD;
        if (orow>=0 && orow<HH && ocol>=0 && ocol<WW_) {
          float sbv = sbl[hd*WS2 + i];
          size_t base = ((size_t)((b*HH + orow)*WW_ + ocol))*CC + hd*32;
          #pragma unroll
          for (int nt = 0; nt < 2; nt++) {
            int c = nt*16 + ln;
            x2[base + c] = x[base + c] + acc[mt][nt][r] + sbv;
          }
        }
      }
    }
  }
}

// ---------------------------------------------------------------------------
// mlp v3: x2 -> LN2 -> fc1+GELU -> fc2 -> +x2 (in-place, f32 I/O, bf16 MFMA)
// 128 tokens / 256 threads / 4 waves; wave = 32 tokens, fully wave-private:
//  - each wave LNs its OWN 32 tokens into its own 8704 B LDS region, hoists
//    them to VGPRs (B-operand frags), then overlays Ht on the same region.
//  - gemm1 runs with operands SWAPPED (A = W1 rows read direct from global
//    L2-resident fc1_wT, B = token frags in VGPRs). D then holds 4
//    consecutive hid per lane -> Ht written with ONE b64 store per tile
//    (2-way bank pattern at stride 72 = free; no swizzle, no scalar stores).
//  - gemm2 is byte-identical to the proven version (A = Ht rows b128,
//    B = fc2_wT [c][hid] frags) except B read direct from global.
//  - weights never touch LDS; no load_ch/store_ch; ZERO __syncthreads.
// LDS 34816 B, launch_bounds(256,3) -> 3 blocks/CU (was 2 at 73 KB).
// ---------------------------------------------------------------------------
__global__ __launch_bounds__(256, 3) void mlp_k(
    float* __restrict__ xio,
    const float* __restrict__ g2, const float* __restrict__ b2,
    const u16* __restrict__ fc1_wT, const float* __restrict__ fc1_b,
    const u16* __restrict__ fc2_wT, const float* __restrict__ fc2_b)
{
  // per-wave 8704 B region: ALn u16[32][136] -> reused as Ht u16[32][72]
  __shared__ __align__(16) char um[4*8704];
  int tid = threadIdx.x;
  int wvid = tid >> 6, lane = tid & 63;
  int ln = lane & 15, qd = lane >> 4;
  int m0 = wvid*32;
  size_t tokbase = (size_t)blockIdx.x * 128;
  u16* ALnW = (u16*)(um + wvid*8704);   // local rows 0..31, stride 136
  u16* Htp  = (u16*)(um + wvid*8704);   // local rows 0..31, stride 72

  // LN2 for this wave's 32 tokens (own region only)
  float gl0 = g2[lane], gl1 = g2[lane+64];
  float bl0 = b2[lane], bl1 = b2[lane+64];
  for (int t = 0; t < 32; ++t) {
    const float* px = xio + (tokbase + m0 + t)*CC;
    float v0 = px[lane], v1 = px[lane+64];
    float s = v0+v1, ss = v0*v0+v1*v1;
    #pragma unroll
    for (int o = 32; o > 0; o >>= 1) { s += __shfl_xor(s,o); ss += __shfl_xor(ss,o); }
    float mu = s*(1.f/128.f), var = ss*(1.f/128.f) - mu*mu;
    float rs = rsqrtf(var + 1e-5f);
    ALnW[t*136 + lane]      = f2bf((v0-mu)*rs*gl0 + bl0);
    ALnW[t*136 + lane + 64] = f2bf((v1-mu)*rs*gl1 + bl1);
  }
  // own-region write->read: DS is in-order per wave; no barrier needed.

  // token frags to VGPRs (B-operand; same lane layout as A for this shape)
  short8 bv[2][4];
  #pragma unroll
  for (int n = 0; n < 2; n++)
    #pragma unroll
    for (int ks = 0; ks < 4; ks++)
      bv[n][ks] = ld_frag(&ALnW[(n*16 + ln)*136 + ks*32 + qd*8]);

  floatx4 oacc[2][8];                 // [m-tile(tok)][n-tile(c)]
  #pragma unroll
  for (int mt = 0; mt < 2; mt++)
    #pragma unroll
    for (int nt = 0; nt < 8; nt++) oacc[mt][nt] = (floatx4){0.f,0.f,0.f,0.f};

  for (int ch = 0; ch < 8; ++ch) {
    // gemm1 (swapped): D'[hid][tok], A = W1 rows (global), B = bv (VGPR)
    #pragma unroll
    for (int kt = 0; kt < 4; ++kt) {
      short8 aw[4];
      #pragma unroll
      for (int ks = 0; ks < 4; ks++)
        aw[ks] = ld_frag_g(&fc1_wT[(size_t)(ch*64 + kt*16 + ln)*CC + ks*32 + qd*8]);
      floatx4 h0 = (floatx4){0.f,0.f,0.f,0.f};
      floatx4 h1 = (floatx4){0.f,0.f,0.f,0.f};
      #pragma unroll
      for (int ks = 0; ks < 4; ks++) {
        h0 = __builtin_amdgcn_mfma_f32_16x16x32_bf16(aw[ks], bv[0][ks], h0, 0, 0, 0);
        h1 = __builtin_amdgcn_mfma_f32_16x16x32_bf16(aw[ks], bv[1][ks], h1, 0, 0, 0);
      }
      // lane holds hid = ch*64 + kt*16 + qd*4 + r for tok = n*16 + ln
      floatx4 bias = *(const floatx4*)&fc1_b[ch*64 + kt*16 + qd*4];
      uint2 u0, u1;
      u0.x = pk2(gelu_f(h0[0]+bias[0]), gelu_f(h0[1]+bias[1]));
      u0.y = pk2(gelu_f(h0[2]+bias[2]), gelu_f(h0[3]+bias[3]));
      u1.x = pk2(gelu_f(h1[0]+bias[0]), gelu_f(h1[1]+bias[1]));
      u1.y = pk2(gelu_f(h1[2]+bias[2]), gelu_f(h1[3]+bias[3]));
      *(uint2*)&Htp[(     ln)*72 + kt*16 + qd*4] = u0;   // tok-tile 0
      *(uint2*)&Htp[(16 + ln)*72 + kt*16 + qd*4] = u1;   // tok-tile 1
    }
    asm volatile("s_waitcnt lgkmcnt(0)" ::: "memory");  // same-wave Ht handoff

    // gemm2 (proven pattern): oacc[32 tok x 128 c] += Ht @ W2-frags
    short8 av2[2][2];
    #pragma unroll
    for (int mt = 0; mt < 2; mt++)
      #pragma unroll
      for (int ks = 0; ks < 2; ks++)
        av2[mt][ks] = ld_frag(&Htp[(mt*16 + ln)*72 + ks*32 + qd*8]);
    #pragma unroll
    for (int nt = 0; nt < 8; nt++) {
      short8 bv2[2];
      #pragma unroll
      for (int ks = 0; ks < 2; ks++)
        bv2[ks] = ld_frag_g(&fc2_wT[(size_t)(nt*16 + ln)*HID + ch*64 + ks*32 + qd*8]);
      #pragma unroll
      for (int mt = 0; mt < 2; mt++)
        #pragma unroll
        for (int ks = 0; ks < 2; ks++)
          oacc[mt][nt] = __builtin_amdgcn_mfma_f32_16x16x32_bf16(av2[mt][ks], bv2[ks], oacc[mt][nt], 0, 0, 0);
    }
  }

  // epilogue: + fc2 bias + residual, in-place
  float bias2[8];
  #pragma unroll
  for (int nt = 0; nt < 8; nt++) bias2[nt] = fc2_b[nt*16 + ln];
  #pragma unroll
  for (int mt = 0; mt < 2; mt++)
    #pragma unroll
    for (int r = 0; r < 4; r++) {
      size_t tok = tokbase + m0 + mt*16 + qd*4 + r;
      float* rowp = xio + tok*CC;
      #pragma unroll
      for (int nt = 0; nt < 8; nt++) {
        int n = nt*16 + ln;
        rowp[n] = rowp[n] + oacc[mt][nt][r] + bias2[nt];
      }
    }
}

extern "C" void kernel_launch(void* const* d_in, const int* in_sizes, int n_in,
                              void* d_out, int out_size, void* d_ws, size_t ws_size,
                              hipStream_t stream) {
  const float* x     = (const float*)d_in[0];
  const float* g1    = (const float*)d_in[1];
  const float* b1    = (const float*)d_in[2];
  const float* sw    = (const float*)d_in[3];
  const float* sb    = (const float*)d_in[4];
  const float* g2    = (const float*)d_in[5];
  const float* b2    = (const float*)d_in[6];
  const float* fc1_w = (const float*)d_in[7];
  const float* fc1_b = (const float*)d_in[8];
  const float* fc2_w = (const float*)d_in[9];
  const float* fc2_b = (const float*)d_in[10];
  float* out = (float*)d_out;

  u16* fc1_wT = (u16*)d_ws;                  // 512*128 bf16 (131072 B)
  u16* fc2_wT = fc1_wT + HID*CC;             // 128*512 bf16 (131072 B)
  u16* swT    = fc2_wT + CC*HID;             // 4*64*68 bf16 (34816 B)

  prep_k<<<64, 256, 0, stream>>>(fc1_w, fc2_w, sw, fc1_wT, fc2_wT, swT);
  winmix_k<<<NB*81, 256, 0, stream>>>(x, g1, b1, swT, sb, out);
  mlp_k<<<(NB*HH*WW_)/128, 256, 0, stream>>>(out, g2, b2, fc1_wT, fc1_b, fc2_wT, fc2_b);
}

// Round 3
// 538.285 us; speedup vs baseline: 1.0207x; 1.0207x over previous
//
#include <hip/hip_runtime.h>

typedef unsigned short u16;
typedef __attribute__((ext_vector_type(8))) short short8;
typedef __attribute__((ext_vector_type(4))) float floatx4;

#define NB 64
#define HH 56
#define WW_ 56
#define CC 128
#define NHEADS 4
#define WS2 49
#define PAD 4      // P_T = P_L = 4
#define HID 512

__device__ __forceinline__ float bf2f(u16 u){ return __uint_as_float(((unsigned)u)<<16); }
__device__ __forceinline__ u16 f2bf(float f){
  unsigned u = __float_as_uint(f);
  return (u16)((u + 0x7FFFu + ((u>>16)&1u)) >> 16);
}
// pack two f32 -> one u32 of 2 bf16 (lo = a, hi = b)
__device__ __forceinline__ unsigned pk2(float a, float b){
  return ((unsigned)f2bf(b) << 16) | (unsigned)f2bf(a);
}
// tanh-approx GELU in sigmoid form: x * sigmoid(1.5957691*x*(1+0.044715*x^2))
__device__ __forceinline__ float gelu_f(float x){
  float u2 = x*(1.5957691216f + 0.0713548162f*x*x);
  return x / (1.f + __expf(-u2));
}
// element-wise fragment load (LDS); compiler merges to widest aligned DS op
__device__ __forceinline__ short8 ld_frag(const u16* p){
  short8 v;
  #pragma unroll
  for (int e = 0; e < 8; e++) v[e] = (short)p[e];
  return v;
}
// vector fragment load (global, provably 16B-aligned)
__device__ __forceinline__ short8 ld_frag_g(const u16* p){
  return *(const short8*)p;
}

// ---------------------------------------------------------------------------
// prep: fc1_w (C,HID) f32 -> bf16 [HID][C];  fc2_w (HID,C) f32 -> bf16 [C][HID]
//       spatial_w [h][i][j] f32 -> bf16 [h][i(64)][j(stride 72)], zero-padded
//       (stride 72 u16 = 144 B -> 16B-aligned rows => b128 LDS frag reads)
// ---------------------------------------------------------------------------
__global__ __launch_bounds__(256) void prep_k(
    const float* __restrict__ fc1_w, const float* __restrict__ fc2_w,
    const float* __restrict__ sw,
    u16* __restrict__ fc1_wT, u16* __restrict__ fc2_wT, u16* __restrict__ swT)
{
  int tid = blockIdx.x*256 + threadIdx.x;
  int nth = gridDim.x * 256;
  for (int idx = tid; idx < HID*CC; idx += nth) {
    int n = idx >> 7, k = idx & 127;
    fc1_wT[idx] = f2bf(fc1_w[k*HID + n]);
  }
  for (int idx = tid; idx < CC*HID; idx += nth) {
    int c = idx >> 9, h = idx & 511;
    fc2_wT[idx] = f2bf(fc2_w[h*CC + c]);
  }
  for (int idx = tid; idx < NHEADS*64*72; idx += nth) {
    int hd = idx / (64*72); int rem = idx - hd*64*72;
    int i = rem / 72, j = rem - i*72;
    swT[idx] = (i < WS2 && j < WS2) ? f2bf(sw[(hd*WS2 + i)*WS2 + j]) : (u16)0;
  }
}

// ---------------------------------------------------------------------------
// winmix v2: fused LN1 + shifted-window token mix (MFMA) + residual -> x2
// one block per (batch, window); wave = head.
// W-frags (stride 72, b128) pulled to VGPRs right after staging, so the
// 36.8 KB wl region is reused for xnt -> LDS 37.6 KB -> up to 4 blocks/CU.
// ---------------------------------------------------------------------------
__global__ __launch_bounds__(256, 3) void winmix_k(
    const float* __restrict__ x, const float* __restrict__ g1, const float* __restrict__ b1,
    const u16* __restrict__ swT, const float* __restrict__ sb,
    float* __restrict__ x2)
{
  // union: wl u16[4][64][72] (36864 B) -> reused as xnt u16[128][66] (16896 B)
  __shared__ __align__(16) char uw[NHEADS*64*72*2];
  __shared__ float sbl[NHEADS*WS2];  // 784 B
  u16* wl  = (u16*)uw;
  u16* xnt = (u16*)uw;
  int tid = threadIdx.x;
  int wvid = tid >> 6, lane = tid & 63;
  int ln = lane & 15, qd = lane >> 4;
  int b = blockIdx.x / 81; int wi = blockIdx.x - b*81;
  int wh = wi / 9, wwn = wi - wh*9;

  { // stage spatial weights: 4*64*72 u16 = 4608 uint2, 18 per thread
    const uint2* ws = (const uint2*)swT;
    uint2* wd = (uint2*)wl;
    #pragma unroll
    for (int r = 0; r < 18; r++) wd[tid + r*256] = ws[tid + r*256];
    if (tid < NHEADS*WS2) sbl[tid] = sb[tid];
  }
  __syncthreads();

  // extract W A-frags to VGPRs (b128: 144 B row stride), then wl is dead
  int hd = wvid;
  const u16* wbase = wl + hd*64*72;
  short8 af[4][2];
  #pragma unroll
  for (int mt = 0; mt < 4; mt++)
    #pragma unroll
    for (int ks = 0; ks < 2; ks++)
      af[mt][ks] = ld_frag(&wbase[(mt*16 + ln)*72 + ks*32 + qd*8]);
  __syncthreads();

  // LN per window position (transposed write into reused region); jj>=49 -> 0
  float gl0 = g1[lane], gl1 = g1[lane+64];
  float bl0 = b1[lane], bl1 = b1[lane+64];
  for (int jj = wvid; jj < 64; jj += 4) {
    u16 o0 = 0, o1 = 0;
    if (jj < WS2) {
      int jr = jj / 7, jc = jj - jr*7;
      int pr = wh*7 + jr - PAD, pc = wwn*7 + jc - PAD;
      bool valid = (pr>=0) & (pr<HH) & (pc>=0) & (pc<WW_);
      float v0 = 0.f, v1 = 0.f;
      const float* px = x + ((size_t)((b*HH + pr)*WW_ + pc))*CC;
      if (valid) { v0 = px[lane]; v1 = px[lane+64]; }
      float s = v0 + v1, ss = v0*v0 + v1*v1;
      #pragma unroll
      for (int o = 32; o > 0; o >>= 1) { s += __shfl_xor(s, o); ss += __shfl_xor(ss, o); }
      float mu = s * (1.f/128.f);
      float var = ss * (1.f/128.f) - mu*mu;
      float rs = rsqrtf(var + 1e-5f);
      if (valid) {
        o0 = f2bf((v0 - mu)*rs*gl0 + bl0);
        o1 = f2bf((v1 - mu)*rs*gl1 + bl1);
      }
    }
    xnt[lane*66 + jj]      = o0;
    xnt[(lane+64)*66 + jj] = o1;
  }
  __syncthreads();

  // MFMA token mix: wave = head
  short8 bf_[2][2];
  #pragma unroll
  for (int nt = 0; nt < 2; nt++)
    #pragma unroll
    for (int ks = 0; ks < 2; ks++)
      bf_[nt][ks] = ld_frag(&xnt[(hd*32 + nt*16 + ln)*66 + ks*32 + qd*8]);
  floatx4 acc[4][2];
  #pragma unroll
  for (int mt = 0; mt < 4; mt++)
    #pragma unroll
    for (int nt = 0; nt < 2; nt++)
      acc[mt][nt] = (floatx4){0.f,0.f,0.f,0.f};
  #pragma unroll
  for (int ks = 0; ks < 2; ks++)
    #pragma unroll
    for (int mt = 0; mt < 4; mt++)
      #pragma unroll
      for (int nt = 0; nt < 2; nt++)
        acc[mt][nt] = __builtin_amdgcn_mfma_f32_16x16x32_bf16(af[mt][ks], bf_[nt][ks], acc[mt][nt], 0, 0, 0);

  // epilogue: residual add + spatial bias + write (skip pad/cropped)
  #pragma unroll
  for (int mt = 0; mt < 4; mt++) {
    #pragma unroll
    for (int r = 0; r < 4; r++) {
      int i = mt*16 + qd*4 + r;
      if (i < WS2) {
        int ir = i / 7, ic = i - ir*7;
        int orow = wh*7 + ir - PAD, ocol = wwn*7 + ic - PAD;
        if (orow>=0 && orow<HH && ocol>=0 && ocol<WW_) {
          float sbv = sbl[hd*WS2 + i];
          size_t base = ((size_t)((b*HH + orow)*WW_ + ocol))*CC + hd*32;
          #pragma unroll
          for (int nt = 0; nt < 2; nt++) {
            int c = nt*16 + ln;
            x2[base + c] = x[base + c] + acc[mt][nt][r] + sbv;
          }
        }
      }
    }
  }
}

// ---------------------------------------------------------------------------
// mlp v4: x2 -> LN2 -> fc1+GELU -> fc2 -> +x2 (in-place, f32 I/O, bf16 MFMA)
// Wave-private (zero __syncthreads), as v3, with the pipeline un-blocked:
//  - the asm "memory" lgkmcnt barrier is GONE. Same-wave DS ops execute in
//    order (CDNA) and the compiler orders Ht ds_read after ds_write via
//    alias analysis, so correctness holds while global weight loads are now
//    free to hoist across the gemm1/GELU/Ht region (v3 pinned VGPR at 72 and
//    exposed ~2x L2 latency per chunk serially).
//  - gemm2 W-frags issued at the top of each chunk (no dependencies) so the
//    scheduler pipelines them under gemm1's MFMAs.
//  - LN2 vectorized to float2 (lane covers channels 2l,2l+1): half the load
//    instrs, single b32 ALn write (2-way bank = free).
// LDS 34816 B; launch_bounds(256,3).
// ---------------------------------------------------------------------------
__global__ __launch_bounds__(256, 3) void mlp_k(
    float* __restrict__ xio,
    const float* __restrict__ g2, const float* __restrict__ b2,
    const u16* __restrict__ fc1_wT, const float* __restrict__ fc1_b,
    const u16* __restrict__ fc2_wT, const float* __restrict__ fc2_b)
{
  // per-wave 8704 B region: ALn u16[32][136] -> reused as Ht u16[32][72]
  __shared__ __align__(16) char um[4*8704];
  int tid = threadIdx.x;
  int wvid = tid >> 6, lane = tid & 63;
  int ln = lane & 15, qd = lane >> 4;
  int m0 = wvid*32;
  size_t tokbase = (size_t)blockIdx.x * 128;
  u16* ALnW = (u16*)(um + wvid*8704);   // local rows 0..31, stride 136
  u16* Htp  = (u16*)(um + wvid*8704);   // local rows 0..31, stride 72

  // LN2 for this wave's 32 tokens (own region only), float2-vectorized
  float2 gl = *(const float2*)&g2[2*lane];
  float2 bl = *(const float2*)&b2[2*lane];
  for (int t = 0; t < 32; ++t) {
    float2 v = *(const float2*)(xio + (tokbase + m0 + t)*CC + 2*lane);
    float s = v.x + v.y, ss = v.x*v.x + v.y*v.y;
    #pragma unroll
    for (int o = 32; o > 0; o >>= 1) { s += __shfl_xor(s,o); ss += __shfl_xor(ss,o); }
    float mu = s*(1.f/128.f), var = ss*(1.f/128.f) - mu*mu;
    float rs = rsqrtf(var + 1e-5f);
    *(unsigned*)&ALnW[t*136 + 2*lane] =
        pk2((v.x-mu)*rs*gl.x + bl.x, (v.y-mu)*rs*gl.y + bl.y);
  }

  // token frags to VGPRs (B-operand; same lane layout as A for this shape)
  short8 bv[2][4];
  #pragma unroll
  for (int n = 0; n < 2; n++)
    #pragma unroll
    for (int ks = 0; ks < 4; ks++)
      bv[n][ks] = ld_frag(&ALnW[(n*16 + ln)*136 + ks*32 + qd*8]);

  floatx4 oacc[2][8];                 // [m-tile(tok)][n-tile(c)]
  #pragma unroll
  for (int mt = 0; mt < 2; mt++)
    #pragma unroll
    for (int nt = 0; nt < 8; nt++) oacc[mt][nt] = (floatx4){0.f,0.f,0.f,0.f};

  for (int ch = 0; ch < 8; ++ch) {
    // gemm2 W-frags: no deps on this chunk -> scheduler hoists them under
    // gemm1's MFMAs (this is the latency-hiding v3 lacked)
    short8 bw[8][2];
    #pragma unroll
    for (int nt = 0; nt < 8; nt++)
      #pragma unroll
      for (int ks = 0; ks < 2; ks++)
        bw[nt][ks] = ld_frag_g(&fc2_wT[(size_t)(nt*16 + ln)*HID + ch*64 + ks*32 + qd*8]);

    // gemm1 (swapped): D'[hid][tok], A = W1 rows (global), B = bv (VGPR)
    #pragma unroll
    for (int kt = 0; kt < 4; ++kt) {
      short8 aw[4];
      #pragma unroll
      for (int ks = 0; ks < 4; ks++)
        aw[ks] = ld_frag_g(&fc1_wT[(size_t)(ch*64 + kt*16 + ln)*CC + ks*32 + qd*8]);
      floatx4 h0 = (floatx4){0.f,0.f,0.f,0.f};
      floatx4 h1 = (floatx4){0.f,0.f,0.f,0.f};
      #pragma unroll
      for (int ks = 0; ks < 4; ks++) {
        h0 = __builtin_amdgcn_mfma_f32_16x16x32_bf16(aw[ks], bv[0][ks], h0, 0, 0, 0);
        h1 = __builtin_amdgcn_mfma_f32_16x16x32_bf16(aw[ks], bv[1][ks], h1, 0, 0, 0);
      }
      // lane holds hid = ch*64 + kt*16 + qd*4 + r for tok = n*16 + ln
      floatx4 bias = *(const floatx4*)&fc1_b[ch*64 + kt*16 + qd*4];
      uint2 u0, u1;
      u0.x = pk2(gelu_f(h0[0]+bias[0]), gelu_f(h0[1]+bias[1]));
      u0.y = pk2(gelu_f(h0[2]+bias[2]), gelu_f(h0[3]+bias[3]));
      u1.x = pk2(gelu_f(h1[0]+bias[0]), gelu_f(h1[1]+bias[1]));
      u1.y = pk2(gelu_f(h1[2]+bias[2]), gelu_f(h1[3]+bias[3]));
      *(uint2*)&Htp[(     ln)*72 + kt*16 + qd*4] = u0;   // tok-tile 0
      *(uint2*)&Htp[(16 + ln)*72 + kt*16 + qd*4] = u1;   // tok-tile 1
    }
    // same-wave DS in-order + compiler alias ordering: no barrier needed

    // gemm2: oacc[32 tok x 128 c] += Ht @ W2-frags
    short8 av2[2][2];
    #pragma unroll
    for (int mt = 0; mt < 2; mt++)
      #pragma unroll
      for (int ks = 0; ks < 2; ks++)
        av2[mt][ks] = ld_frag(&Htp[(mt*16 + ln)*72 + ks*32 + qd*8]);
    #pragma unroll
    for (int nt = 0; nt < 8; nt++)
      #pragma unroll
      for (int mt = 0; mt < 2; mt++)
        #pragma unroll
        for (int ks = 0; ks < 2; ks++)
          oacc[mt][nt] = __builtin_amdgcn_mfma_f32_16x16x32_bf16(av2[mt][ks], bw[nt][ks], oacc[mt][nt], 0, 0, 0);
  }

  // epilogue: + fc2 bias + residual, in-place
  float bias2[8];
  #pragma unroll
  for (int nt = 0; nt < 8; nt++) bias2[nt] = fc2_b[nt*16 + ln];
  #pragma unroll
  for (int mt = 0; mt < 2; mt++)
    #pragma unroll
    for (int r = 0; r < 4; r++) {
      size_t tok = tokbase + m0 + mt*16 + qd*4 + r;
      float* rowp = xio + tok*CC;
      #pragma unroll
      for (int nt = 0; nt < 8; nt++) {
        int n = nt*16 + ln;
        rowp[n] = rowp[n] + oacc[mt][nt][r] + bias2[nt];
      }
    }
}

extern "C" void kernel_launch(void* const* d_in, const int* in_sizes, int n_in,
                              void* d_out, int out_size, void* d_ws, size_t ws_size,
                              hipStream_t stream) {
  const float* x     = (const float*)d_in[0];
  const float* g1    = (const float*)d_in[1];
  const float* b1    = (const float*)d_in[2];
  const float* sw    = (const float*)d_in[3];
  const float* sb    = (const float*)d_in[4];
  const float* g2    = (const float*)d_in[5];
  const float* b2    = (const float*)d_in[6];
  const float* fc1_w = (const float*)d_in[7];
  const float* fc1_b = (const float*)d_in[8];
  const float* fc2_w = (const float*)d_in[9];
  const float* fc2_b = (const float*)d_in[10];
  float* out = (float*)d_out;

  u16* fc1_wT = (u16*)d_ws;                  // 512*128 bf16 (131072 B)
  u16* fc2_wT = fc1_wT + HID*CC;             // 128*512 bf16 (131072 B)
  u16* swT    = fc2_wT + CC*HID;             // 4*64*72 bf16 (36864 B)

  prep_k<<<64, 256, 0, stream>>>(fc1_w, fc2_w, sw, fc1_wT, fc2_wT, swT);
  winmix_k<<<NB*81, 256, 0, stream>>>(x, g1, b1, swT, sb, out);
  mlp_k<<<(NB*HH*WW_)/128, 256, 0, stream>>>(out, g2, b2, fc1_wT, fc1_b, fc2_wT, fc2_b);
}

// Round 4
// 500.641 us; speedup vs baseline: 1.0974x; 1.0752x over previous
//
#include <hip/hip_runtime.h>

typedef unsigned short u16;
typedef __attribute__((ext_vector_type(8))) short short8;
typedef __attribute__((ext_vector_type(4))) float floatx4;

#define NB 64
#define HH 56
#define WW_ 56
#define CC 128
#define NHEADS 4
#define WS2 49
#define PAD 4      // P_T = P_L = 4
#define HID 512

__device__ __forceinline__ float bf2f(u16 u){ return __uint_as_float(((unsigned)u)<<16); }
__device__ __forceinline__ u16 f2bf(float f){
  unsigned u = __float_as_uint(f);
  return (u16)((u + 0x7FFFu + ((u>>16)&1u)) >> 16);
}
// pack two f32 -> one u32 of 2 bf16 (lo = a, hi = b)
__device__ __forceinline__ unsigned pk2(float a, float b){
  return ((unsigned)f2bf(b) << 16) | (unsigned)f2bf(a);
}
// tanh-approx GELU in sigmoid form: x * sigmoid(1.5957691*x*(1+0.044715*x^2))
__device__ __forceinline__ float gelu_f(float x){
  float u2 = x*(1.5957691216f + 0.0713548162f*x*x);
  return x / (1.f + __expf(-u2));
}
// element-wise fragment load (LDS); compiler merges to widest aligned DS op
__device__ __forceinline__ short8 ld_frag(const u16* p){
  short8 v;
  #pragma unroll
  for (int e = 0; e < 8; e++) v[e] = (short)p[e];
  return v;
}

// ---------------------------------------------------------------------------
// prep: fc1_w (C,HID) f32 -> bf16 [HID][C];  fc2_w (HID,C) f32 -> bf16 [C][HID]
//       spatial_w [h][i][j] f32 -> bf16 [h][i(64)][j(stride 72)], zero-padded
// ---------------------------------------------------------------------------
__global__ __launch_bounds__(256) void prep_k(
    const float* __restrict__ fc1_w, const float* __restrict__ fc2_w,
    const float* __restrict__ sw,
    u16* __restrict__ fc1_wT, u16* __restrict__ fc2_wT, u16* __restrict__ swT)
{
  int tid = blockIdx.x*256 + threadIdx.x;
  int nth = gridDim.x * 256;
  for (int idx = tid; idx < HID*CC; idx += nth) {
    int n = idx >> 7, k = idx & 127;
    fc1_wT[idx] = f2bf(fc1_w[k*HID + n]);
  }
  for (int idx = tid; idx < CC*HID; idx += nth) {
    int c = idx >> 9, h = idx & 511;
    fc2_wT[idx] = f2bf(fc2_w[h*CC + c]);
  }
  for (int idx = tid; idx < NHEADS*64*72; idx += nth) {
    int hd = idx / (64*72); int rem = idx - hd*64*72;
    int i = rem / 72, j = rem - i*72;
    swT[idx] = (i < WS2 && j < WS2) ? f2bf(sw[(hd*WS2 + i)*WS2 + j]) : (u16)0;
  }
}

// ---------------------------------------------------------------------------
// winmix v2: fused LN1 + shifted-window token mix (MFMA) + residual -> x2
// one block per (batch, window); wave = head. W-frags hoisted to VGPRs so
// the wl region is reused for xnt -> LDS 37.6 KB. (unchanged this round)
// ---------------------------------------------------------------------------
__global__ __launch_bounds__(256, 3) void winmix_k(
    const float* __restrict__ x, const float* __restrict__ g1, const float* __restrict__ b1,
    const u16* __restrict__ swT, const float* __restrict__ sb,
    float* __restrict__ x2)
{
  // union: wl u16[4][64][72] (36864 B) -> reused as xnt u16[128][66] (16896 B)
  __shared__ __align__(16) char uw[NHEADS*64*72*2];
  __shared__ float sbl[NHEADS*WS2];  // 784 B
  u16* wl  = (u16*)uw;
  u16* xnt = (u16*)uw;
  int tid = threadIdx.x;
  int wvid = tid >> 6, lane = tid & 63;
  int ln = lane & 15, qd = lane >> 4;
  int b = blockIdx.x / 81; int wi = blockIdx.x - b*81;
  int wh = wi / 9, wwn = wi - wh*9;

  { // stage spatial weights: 4*64*72 u16 = 4608 uint2, 18 per thread
    const uint2* ws = (const uint2*)swT;
    uint2* wd = (uint2*)wl;
    #pragma unroll
    for (int r = 0; r < 18; r++) wd[tid + r*256] = ws[tid + r*256];
    if (tid < NHEADS*WS2) sbl[tid] = sb[tid];
  }
  __syncthreads();

  // extract W A-frags to VGPRs (b128: 144 B row stride), then wl is dead
  int hd = wvid;
  const u16* wbase = wl + hd*64*72;
  short8 af[4][2];
  #pragma unroll
  for (int mt = 0; mt < 4; mt++)
    #pragma unroll
    for (int ks = 0; ks < 2; ks++)
      af[mt][ks] = ld_frag(&wbase[(mt*16 + ln)*72 + ks*32 + qd*8]);
  __syncthreads();

  // LN per window position (transposed write into reused region); jj>=49 -> 0
  float gl0 = g1[lane], gl1 = g1[lane+64];
  float bl0 = b1[lane], bl1 = b1[lane+64];
  for (int jj = wvid; jj < 64; jj += 4) {
    u16 o0 = 0, o1 = 0;
    if (jj < WS2) {
      int jr = jj / 7, jc = jj - jr*7;
      int pr = wh*7 + jr - PAD, pc = wwn*7 + jc - PAD;
      bool valid = (pr>=0) & (pr<HH) & (pc>=0) & (pc<WW_);
      float v0 = 0.f, v1 = 0.f;
      const float* px = x + ((size_t)((b*HH + pr)*WW_ + pc))*CC;
      if (valid) { v0 = px[lane]; v1 = px[lane+64]; }
      float s = v0 + v1, ss = v0*v0 + v1*v1;
      #pragma unroll
      for (int o = 32; o > 0; o >>= 1) { s += __shfl_xor(s, o); ss += __shfl_xor(ss, o); }
      float mu = s * (1.f/128.f);
      float var = ss * (1.f/128.f) - mu*mu;
      float rs = rsqrtf(var + 1e-5f);
      if (valid) {
        o0 = f2bf((v0 - mu)*rs*gl0 + bl0);
        o1 = f2bf((v1 - mu)*rs*gl1 + bl1);
      }
    }
    xnt[lane*66 + jj]      = o0;
    xnt[(lane+64)*66 + jj] = o1;
  }
  __syncthreads();

  // MFMA token mix: wave = head
  short8 bf_[2][2];
  #pragma unroll
  for (int nt = 0; nt < 2; nt++)
    #pragma unroll
    for (int ks = 0; ks < 2; ks++)
      bf_[nt][ks] = ld_frag(&xnt[(hd*32 + nt*16 + ln)*66 + ks*32 + qd*8]);
  floatx4 acc[4][2];
  #pragma unroll
  for (int mt = 0; mt < 4; mt++)
    #pragma unroll
    for (int nt = 0; nt < 2; nt++)
      acc[mt][nt] = (floatx4){0.f,0.f,0.f,0.f};
  #pragma unroll
  for (int ks = 0; ks < 2; ks++)
    #pragma unroll
    for (int mt = 0; mt < 4; mt++)
      #pragma unroll
      for (int nt = 0; nt < 2; nt++)
        acc[mt][nt] = __builtin_amdgcn_mfma_f32_16x16x32_bf16(af[mt][ks], bf_[nt][ks], acc[mt][nt], 0, 0, 0);

  // epilogue: residual add + spatial bias + write (skip pad/cropped)
  #pragma unroll
  for (int mt = 0; mt < 4; mt++) {
    #pragma unroll
    for (int r = 0; r < 4; r++) {
      int i = mt*16 + qd*4 + r;
      if (i < WS2) {
        int ir = i / 7, ic = i - ir*7;
        int orow = wh*7 + ir - PAD, ocol = wwn*7 + ic - PAD;
        if (orow>=0 && orow<HH && ocol>=0 && ocol<WW_) {
          float sbv = sbl[hd*WS2 + i];
          size_t base = ((size_t)((b*HH + orow)*WW_ + ocol))*CC + hd*32;
          #pragma unroll
          for (int nt = 0; nt < 2; nt++) {
            int c = nt*16 + ln;
            x2[base + c] = x[base + c] + acc[mt][nt][r] + sbv;
          }
        }
      }
    }
  }
}

// ---------------------------------------------------------------------------
// mlp v5: x2 -> LN2 -> fc1+GELU -> fc2 -> +x2 (in-place, f32 I/O, bf16 MFMA)
// = v2-original's PROVEN pipeline (cooperative LDS weight staging with
//   register prefetch one chunk ahead, same barrier skeleton), with the Ht
//   handoff replaced by the PROVEN swapped-gemm1 core:
//   gemm1 computes D'[hid][tok] (A = W1 rows from B1p, B = token frags in
//   VGPRs) so each lane holds 4 consecutive hid -> Ht written with two b64
//   stores per kt (no XOR swizzle, no scalar u16 stores, no asm barrier;
//   same-wave DS alias ordering suffices - verified in v3/v4).
// Layout diet: Ht stride 68 (8B-aligned), biases read from L2-hot global ->
// LDS 53248 B (was 73216) -> 3 blocks/CU with launch_bounds(256,3).
// ---------------------------------------------------------------------------
__global__ __launch_bounds__(256, 3) void mlp_k(
    float* __restrict__ xio,
    const float* __restrict__ g2, const float* __restrict__ b2,
    const u16* __restrict__ fc1_wT, const float* __restrict__ fc1_b,
    const u16* __restrict__ fc2_wT, const float* __restrict__ fc2_b)
{
  // phase A: ALn u16[128][136] (34816 B)
  // phase B: B1p u16[64][136] @0 (17408) | B2p u16[128][72] @17408 (18432)
  //          | Ht u16[4][32][68] @35840 (17408)  -> union = 53248 B
  __shared__ __align__(16) char um[53248];
  u16* ALn = (u16*)um;
  u16* B1p = (u16*)um;
  u16* B2p = (u16*)(um + 17408);
  int tid = threadIdx.x;
  int wvid = tid >> 6, lane = tid & 63;
  int ln = lane & 15, qd = lane >> 4;
  int m0 = wvid*32;
  size_t tokbase = (size_t)blockIdx.x * 128;
  u16* Htp = (u16*)(um + 35840) + wvid*(32*68);

  // weight staging machinery (register prefetch, one chunk ahead)
  const uint4* src1 = (const uint4*)fc1_wT;   // row = 128 u16 = 16 uint4
  const uint4* src2 = (const uint4*)fc2_wT;   // row = 512 u16 = 64 uint4
  uint4 p1[4], p2[4];
  int n1[4], q1[4], n2[4], q2[4];
  #pragma unroll
  for (int r = 0; r < 4; r++) {
    int idx = tid + r*256;
    n1[r] = idx >> 4; q1[r] = idx & 15;
    n2[r] = idx >> 3; q2[r] = idx & 7;
  }
  auto load_ch = [&](int cc){
    #pragma unroll
    for (int r = 0; r < 4; r++) {
      p1[r] = src1[(cc*64 + n1[r])*16 + q1[r]];
      p2[r] = src2[n2[r]*64 + cc*8 + q2[r]];
    }
  };
  auto store_ch = [&](){
    uint4* d1 = (uint4*)B1p; uint4* d2 = (uint4*)B2p;
    #pragma unroll
    for (int r = 0; r < 4; r++) {
      d1[n1[r]*17 + q1[r]] = p1[r];   // 136 u16 = 17 uint4
      d2[n2[r]*9  + q2[r]] = p2[r];   // 72 u16 = 9 uint4
    }
  };
  load_ch(0);                         // chunk-0 weight fetch overlaps LN2

  // LN2 into ALn (128 tokens, cooperative), float2-vectorized
  float2 gl = *(const float2*)&g2[2*lane];
  float2 bl = *(const float2*)&b2[2*lane];
  for (int t = wvid; t < 128; t += 4) {
    float2 v = *(const float2*)(xio + (tokbase + t)*CC + 2*lane);
    float s = v.x + v.y, ss = v.x*v.x + v.y*v.y;
    #pragma unroll
    for (int o = 32; o > 0; o >>= 1) { s += __shfl_xor(s,o); ss += __shfl_xor(ss,o); }
    float mu = s*(1.f/128.f), var = ss*(1.f/128.f) - mu*mu;
    float rs = rsqrtf(var + 1e-5f);
    *(unsigned*)&ALn[t*136 + 2*lane] =
        pk2((v.x-mu)*rs*gl.x + bl.x, (v.y-mu)*rs*gl.y + bl.y);
  }
  __syncthreads();

  // token B-frags to VGPRs (ALn dead afterwards)
  short8 bv[2][4];
  #pragma unroll
  for (int n = 0; n < 2; n++)
    #pragma unroll
    for (int ks = 0; ks < 4; ks++)
      bv[n][ks] = ld_frag(&ALn[(m0 + n*16 + ln)*136 + ks*32 + qd*8]);
  __syncthreads();

  store_ch();
  __syncthreads();

  floatx4 oacc[2][8];                 // [m-tile(tok)][n-tile(c)]
  #pragma unroll
  for (int mt = 0; mt < 2; mt++)
    #pragma unroll
    for (int nt = 0; nt < 8; nt++) oacc[mt][nt] = (floatx4){0.f,0.f,0.f,0.f};

  for (int ch = 0; ch < 8; ch++) {
    if (ch < 7) load_ch(ch+1);        // prefetch next chunk into VGPRs

    // gemm1 (swapped): D'[hid][tok], A = W1 rows (B1p LDS), B = bv (VGPR)
    #pragma unroll
    for (int kt = 0; kt < 4; ++kt) {
      short8 aw[4];
      #pragma unroll
      for (int ks = 0; ks < 4; ks++)
        aw[ks] = ld_frag(&B1p[(kt*16 + ln)*136 + ks*32 + qd*8]);
      floatx4 h0 = (floatx4){0.f,0.f,0.f,0.f};
      floatx4 h1 = (floatx4){0.f,0.f,0.f,0.f};
      #pragma unroll
      for (int ks = 0; ks < 4; ks++) {
        h0 = __builtin_amdgcn_mfma_f32_16x16x32_bf16(aw[ks], bv[0][ks], h0, 0, 0, 0);
        h1 = __builtin_amdgcn_mfma_f32_16x16x32_bf16(aw[ks], bv[1][ks], h1, 0, 0, 0);
      }
      // lane holds hid = ch*64 + kt*16 + qd*4 + r for tok = n*16 + ln
      floatx4 bias = *(const floatx4*)&fc1_b[ch*64 + kt*16 + qd*4];
      uint2 u0, u1;
      u0.x = pk2(gelu_f(h0[0]+bias[0]), gelu_f(h0[1]+bias[1]));
      u0.y = pk2(gelu_f(h0[2]+bias[2]), gelu_f(h0[3]+bias[3]));
      u1.x = pk2(gelu_f(h1[0]+bias[0]), gelu_f(h1[1]+bias[1]));
      u1.y = pk2(gelu_f(h1[2]+bias[2]), gelu_f(h1[3]+bias[3]));
      *(uint2*)&Htp[(     ln)*68 + kt*16 + qd*4] = u0;   // tok-tile 0
      *(uint2*)&Htp[(16 + ln)*68 + kt*16 + qd*4] = u1;   // tok-tile 1
    }
    // same-wave DS in-order + compiler alias ordering: no barrier needed

    // gemm2: oacc[32 tok x 128 c] += Ht @ W2-frags (B2p LDS)
    short8 av2[2][2];
    #pragma unroll
    for (int mt = 0; mt < 2; mt++)
      #pragma unroll
      for (int ks = 0; ks < 2; ks++)
        av2[mt][ks] = ld_frag(&Htp[(mt*16 + ln)*68 + ks*32 + qd*8]);
    #pragma unroll
    for (int nt = 0; nt < 8; nt++) {
      short8 bv2[2];
      #pragma unroll
      for (int ks = 0; ks < 2; ks++)
        bv2[ks] = ld_frag(&B2p[(nt*16 + ln)*72 + ks*32 + qd*8]);
      #pragma unroll
      for (int mt = 0; mt < 2; mt++)
        #pragma unroll
        for (int ks = 0; ks < 2; ks++)
          oacc[mt][nt] = __builtin_amdgcn_mfma_f32_16x16x32_bf16(av2[mt][ks], bv2[ks], oacc[mt][nt], 0, 0, 0);
    }
    __syncthreads();                  // all waves done reading B1/B2
    if (ch < 7) { store_ch(); __syncthreads(); }
  }

  // epilogue: + fc2 bias + residual, in-place
  float bias2[8];
  #pragma unroll
  for (int nt = 0; nt < 8; nt++) bias2[nt] = fc2_b[nt*16 + ln];
  #pragma unroll
  for (int mt = 0; mt < 2; mt++)
    #pragma unroll
    for (int r = 0; r < 4; r++) {
      size_t tok = tokbase + m0 + mt*16 + qd*4 + r;
      float* rowp = xio + tok*CC;
      #pragma unroll
      for (int nt = 0; nt < 8; nt++) {
        int n = nt*16 + ln;
        rowp[n] = rowp[n] + oacc[mt][nt][r] + bias2[nt];
      }
    }
}

extern "C" void kernel_launch(void* const* d_in, const int* in_sizes, int n_in,
                              void* d_out, int out_size, void* d_ws, size_t ws_size,
                              hipStream_t stream) {
  const float* x     = (const float*)d_in[0];
  const float* g1    = (const float*)d_in[1];
  const float* b1    = (const float*)d_in[2];
  const float* sw    = (const float*)d_in[3];
  const float* sb    = (const float*)d_in[4];
  const float* g2    = (const float*)d_in[5];
  const float* b2    = (const float*)d_in[6];
  const float* fc1_w = (const float*)d_in[7];
  const float* fc1_b = (const float*)d_in[8];
  const float* fc2_w = (const float*)d_in[9];
  const float* fc2_b = (const float*)d_in[10];
  float* out = (float*)d_out;

  u16* fc1_wT = (u16*)d_ws;                  // 512*128 bf16 (131072 B)
  u16* fc2_wT = fc1_wT + HID*CC;             // 128*512 bf16 (131072 B)
  u16* swT    = fc2_wT + CC*HID;             // 4*64*72 bf16 (36864 B)

  prep_k<<<64, 256, 0, stream>>>(fc1_w, fc2_w, sw, fc1_wT, fc2_wT, swT);
  winmix_k<<<NB*81, 256, 0, stream>>>(x, g1, b1, swT, sb, out);
  mlp_k<<<(NB*HH*WW_)/128, 256, 0, stream>>>(out, g2, b2, fc1_wT, fc1_b, fc2_wT, fc2_b);
}